// Round 1
// baseline (726.585 us; speedup 1.0000x reference)
//
#include <hip/hip_runtime.h>
#include <cfloat>
#include <math.h>

#define N 96
#define DIN 16
#define HID 256
#define LAT 128
#define EDGE 4656
#define OUTDIM 6192

// ---- workspace float offsets ----
enum {
  W_H1   = 0,               // 96*256
  W_X1   = 24576,           // 96*256
  W_H2   = 49152,           // 96*256
  W_GH   = 73728,           // 256
  W_H1D  = 73984,           // 128
  W_KL   = 74112,           // 1
  W_OUTP = 74116,           // 4656 (sigmoid edge probs)
  W_OUTX = 78772,           // 1536
  W_RECON= 80308,           // 9216
  W_DEGT = 89524,           // 96
  W_DEGR = 89620,           // 96
  W_DT   = 89716,           // 96
  W_DR   = 89812,           // 96
  W_A    = 89908,           // 9216
  W_B    = 99124,           // 9216
  W_SDT  = 108340,          // 9216  Sdiag transposed: SdT[a][i]
  W_XA   = 117556,          // 9216  ping
  W_XB   = 126772,          // 9216  pong
  W_SSP  = 135988,          // 2*96  norm^2 partials (ping-pong)
  W_IND  = 136180,          // 96 ints
  W_TOTAL= 136280
};

// h1 = (adj @ feats) @ conv1_w ; block = row i, 256 threads (one per out col)
__global__ void k_enc1(const float* __restrict__ adj, const float* __restrict__ feats,
                       const float* __restrict__ w1, float* __restrict__ h1) {
  int i = blockIdx.x, t = threadIdx.x;
  __shared__ float p[16][17];
  __shared__ float t1[16];
  int k = t & 15, part = t >> 4;
  float s = 0.f;
  for (int j = part * 6; j < part * 6 + 6; ++j) s += adj[i * N + j] * feats[j * DIN + k];
  p[part][k] = s;
  __syncthreads();
  if (t < 16) { float q = 0.f; for (int r = 0; r < 16; ++r) q += p[r][t]; t1[t] = q; }
  __syncthreads();
  float h = 0.f;
  for (int kk = 0; kk < 16; ++kk) h += t1[kk] * w1[kk * HID + t];
  h1[i * HID + t] = h;
}

// BN1 (training-mode, biased var) + ReLU ; block = column c, 128 threads (96 rows)
__global__ void k_bn1(const float* __restrict__ h1, const float* __restrict__ gg,
                      const float* __restrict__ bb, float* __restrict__ x1) {
  int c = blockIdx.x, t = threadIdx.x;
  float v = (t < N) ? h1[t * HID + c] : 0.f;
  __shared__ float s1[128], s2[128];
  s1[t] = v; s2[t] = v * v; __syncthreads();
  for (int s = 64; s > 0; s >>= 1) { if (t < s) { s1[t] += s1[t + s]; s2[t] += s2[t + s]; } __syncthreads(); }
  float mu = s1[0] / (float)N;
  float var = s2[0] / (float)N - mu * mu;
  float inv = rsqrtf(var + 1e-5f);
  if (t < N) x1[t * HID + c] = fmaxf((v - mu) * inv * gg[c] + bb[c], 0.f);
}

// h2 = (adj @ x1) @ conv2_w ; block = row i, 256 threads
__global__ void k_enc2(const float* __restrict__ adj, const float* __restrict__ x1,
                       const float* __restrict__ w2, float* __restrict__ h2) {
  int i = blockIdx.x, t = threadIdx.x;
  __shared__ float t2[HID];
  float s = 0.f;
  for (int j = 0; j < N; ++j) s += adj[i * N + j] * x1[j * HID + t];
  t2[t] = s;
  __syncthreads();
  float h = 0.f;
  for (int k = 0; k < HID; ++k) h += t2[k] * w2[k * HID + t];
  h2[i * HID + t] = h;
}

// BN2 (no relu) then gh[c] = column sum ; block = column c
__global__ void k_bn2gh(const float* __restrict__ h2, const float* __restrict__ gg,
                        const float* __restrict__ bb, float* __restrict__ gh) {
  int c = blockIdx.x, t = threadIdx.x;
  float v = (t < N) ? h2[t * HID + c] : 0.f;
  __shared__ float s1[128], s2[128];
  s1[t] = v; s2[t] = v * v; __syncthreads();
  for (int s = 64; s > 0; s >>= 1) { if (t < s) { s1[t] += s1[t + s]; s2[t] += s2[t + s]; } __syncthreads(); }
  float mu = s1[0] / (float)N;
  float var = s2[0] / (float)N - mu * mu;
  float inv = rsqrtf(var + 1e-5f);
  __syncthreads();
  float xv = (t < N) ? ((v - mu) * inv * gg[c] + bb[c]) : 0.f;
  s1[t] = xv; __syncthreads();
  for (int s = 64; s > 0; s >>= 1) { if (t < s) s1[t] += s1[t + s]; __syncthreads(); }
  if (t == 0) gh[c] = s1[0];
}

// VAE: z_mu,z_ls -> z -> h1d = relu(d1 z + b); also KL. 1 block, 128 threads
__global__ void k_vae(const float* __restrict__ gh,
                      const float* __restrict__ e11w, const float* __restrict__ e11b,
                      const float* __restrict__ e12w, const float* __restrict__ e12b,
                      const float* __restrict__ d1w, const float* __restrict__ d1b,
                      const float* __restrict__ eps, float* __restrict__ h1d,
                      float* __restrict__ kl) {
  int t = threadIdx.x;
  __shared__ float ghs[HID];
  ghs[t] = gh[t]; ghs[t + 128] = gh[t + 128];
  __syncthreads();
  float a = e11b[t], c = e12b[t];
  for (int k = 0; k < HID; ++k) { a += e11w[t * HID + k] * ghs[k]; c += e12w[t * HID + k] * ghs[k]; }
  float zv = eps[t] * expf(0.5f * c) + a;
  __shared__ float zs[LAT];
  __shared__ float kr[128];
  zs[t] = zv;
  kr[t] = 1.f + c - a * a - expf(c);
  __syncthreads();
  for (int s = 64; s > 0; s >>= 1) { if (t < s) kr[t] += kr[t + s]; __syncthreads(); }
  if (t == 0) kl[0] = -0.5f * kr[0] / (float)(N * N);
  float hv = d1b[t];
  for (int k = 0; k < LAT; ++k) hv += d1w[t * LAT + k] * zs[k];
  h1d[t] = fmaxf(hv, 0.f);
}

// h_dec = d2_w @ h1d + d2_b ; sigmoid on first EDGE entries
__global__ void k_dec(const float* __restrict__ d2w, const float* __restrict__ d2b,
                      const float* __restrict__ h1d, float* __restrict__ outp,
                      float* __restrict__ outx) {
  __shared__ float hl[LAT];
  int t = threadIdx.x;
  if (t < LAT) hl[t] = h1d[t];
  __syncthreads();
  int o = blockIdx.x * 256 + t;
  if (o < OUTDIM) {
    float s = d2b[o];
    const float* wr = d2w + o * LAT;
    for (int k = 0; k < LAT; ++k) s += wr[k] * hl[k];
    if (o < EDGE) outp[o] = 1.f / (1.f + expf(-s));
    else outx[o - EDGE] = s;
  }
}

// recon matrix + degrees + diagonals ; block = row a, 128 threads
__global__ void k_recon(const float* __restrict__ adj, const float* __restrict__ outp,
                        float* __restrict__ recon, float* __restrict__ degt,
                        float* __restrict__ degr, float* __restrict__ dt,
                        float* __restrict__ dr) {
  int a = blockIdx.x, t = threadIdx.x;
  float rv = 0.f, av = 0.f;
  if (t < N) {
    int i = min(a, t), j = max(a, t);
    int e = i * N - (i * (i - 1)) / 2 + (j - i);
    rv = outp[e];
    av = adj[a * N + t];
    recon[a * N + t] = rv;
    if (t == a) { dr[a] = rv; dt[a] = av; }
  }
  __shared__ float s1[128], s2[128];
  s1[t] = rv; s2[t] = av; __syncthreads();
  for (int s = 64; s > 0; s >>= 1) { if (t < s) { s1[t] += s1[t + s]; s2[t] += s2[t + s]; } __syncthreads(); }
  if (t == 0) { degr[a] = s1[0]; degt[a] = s2[0]; }
}

// A, B, Sdiag^T, x0 init ; block = row a
__global__ void k_simab(const float* __restrict__ adj, const float* __restrict__ recon,
                        const float* __restrict__ degt, const float* __restrict__ degr,
                        const float* __restrict__ dt, const float* __restrict__ dr,
                        float* __restrict__ Am, float* __restrict__ Bm,
                        float* __restrict__ SdT, float* __restrict__ x0) {
  int a = blockIdx.x, t = threadIdx.x;
  if (t < N) {
    Bm[a * N + t] = (t == a) ? 0.f : recon[a * N + t] * dr[a] * dr[t];
    Am[a * N + t] = (t == a) ? 0.f : adj[a * N + t] * dt[a] * dt[t];
    float sim = 1.f / (fabsf(degt[t] - degr[a]) + 1.f);
    SdT[a * N + t] = dt[t] * dr[a] * sim;      // Sdiag[i=t, a]
    x0[a * N + t] = 1.f / (float)N;
  }
}

// one MPM iteration: block a computes column a of x_next.
// M[j] = max_b B[a,b]*x[j,b];  xn[i,a] = inv*(x[i,a]*Sd[i] + sum_j A[i,j]*M[j])
// inv = rsqrt(||x_prev||^2) from per-column partials (lazy normalization).
__global__ void k_mpm(const float* __restrict__ xin, float* __restrict__ xout,
                      const float* __restrict__ sspPrev, float* __restrict__ sspCur,
                      const float* __restrict__ Bm, const float* __restrict__ SdT,
                      const float* __restrict__ Am, int first) {
  int a = blockIdx.x, t = threadIdx.x; // 128 threads
  __shared__ float Bs[N], Sd[N], Ms[N];
  __shared__ float sred[128];
  if (t < N) { Bs[t] = Bm[a * N + t]; Sd[t] = SdT[a * N + t]; }
  sred[t] = (!first && t < N) ? sspPrev[t] : 0.f;
  __syncthreads();
  for (int s = 64; s > 0; s >>= 1) { if (t < s) sred[t] += sred[t + s]; __syncthreads(); }
  float inv = first ? 1.f : rsqrtf(sred[0]);
  int g = t >> 2, l4 = t & 3;
  for (int jj = 0; jj < 3; ++jj) {
    int j = g + (jj << 5);
    const float* xr = xin + j * N;
    float m = 0.f;   // all terms >= 0 (x>=0, B>=0); b==a term is exactly 0
    for (int k = 0; k < 24; ++k) { int b2 = l4 + (k << 2); m = fmaxf(m, Bs[b2] * xr[b2]); }
    m = fmaxf(m, __shfl_xor(m, 1));
    m = fmaxf(m, __shfl_xor(m, 2));
    if (l4 == 0) Ms[j] = m;
  }
  __syncthreads();
  float myss = 0.f;
  for (int ii = 0; ii < 3; ++ii) {
    int i = g + (ii << 5);
    const float* ar = Am + i * N;
    float s = 0.f;
    for (int k = 0; k < 24; ++k) { int j = l4 + (k << 2); s += ar[j] * Ms[j]; }
    s += __shfl_xor(s, 1);
    s += __shfl_xor(s, 2);
    if (l4 == 0) {
      float v = (xin[i * N + a] * Sd[i] + s) * inv;
      xout[i * N + a] = v;
      myss += v * v;
    }
  }
  __syncthreads();
  sred[t] = myss; __syncthreads();
  for (int s = 64; s > 0; s >>= 1) { if (t < s) sred[t] += sred[t + s]; __syncthreads(); }
  if (t == 0) sspCur[a] = sred[0];
}

// greedy max-assignment, exact first-index tie-break (matches jnp.argmax). 1 block, 256 thr
__global__ void k_greedy(const float* __restrict__ xfin, int* __restrict__ ind) {
  int t = threadIdx.x;
  int lane = t & 63, wid = t >> 6;
  __shared__ float xs[N * N];
  __shared__ float wbv[4];
  __shared__ int wbi[4];
  __shared__ int rc[2];
  __shared__ int indS[N];
  for (int e = t; e < N * N; e += 256) xs[e] = xfin[e];
  __syncthreads();
  for (int step = 0; step < N; ++step) {
    float bv = -FLT_MAX; int bi = N * N;
    int base = t * 36;                     // contiguous chunk keeps flat-index order
    for (int q = 0; q < 36; ++q) { float v = xs[base + q]; if (v > bv) { bv = v; bi = base + q; } }
    for (int off = 32; off > 0; off >>= 1) {
      float ov = __shfl_down(bv, off); int oi = __shfl_down(bi, off);
      if (ov > bv || (ov == bv && oi < bi)) { bv = ov; bi = oi; }
    }
    if (lane == 0) { wbv[wid] = bv; wbi[wid] = bi; }
    __syncthreads();
    if (t == 0) {
      float fv = wbv[0]; int fi = wbi[0];
      for (int w = 1; w < 4; ++w) if (wbv[w] > fv || (wbv[w] == fv && wbi[w] < fi)) { fv = wbv[w]; fi = wbi[w]; }
      int r = fi / N, c = fi - (fi / N) * N;
      rc[0] = r; rc[1] = c; indS[c] = r;
    }
    __syncthreads();
    int r = rc[0], c = rc[1];
    if (t < N) { xs[r * N + t] = -FLT_MAX; xs[t * N + c] = -FLT_MAX; }
    __syncthreads();
  }
  if (t < N) ind[t] = indS[t];
}

// final losses: fea MSE + BCE (naive log forms with -100 clip, matching ref) + KL
__global__ void k_loss(const float* __restrict__ adj, const float* __restrict__ feats,
                       const float* __restrict__ outp, const float* __restrict__ outx,
                       const int* __restrict__ ind, const float* __restrict__ kl,
                       float* __restrict__ out) {
  int t = threadIdx.x; // 256
  __shared__ int indS[N];
  if (t < N) indS[t] = ind[t];
  __syncthreads();
  float acc_f = 0.f;
  for (int p = t; p < N * DIN; p += 256) {
    int i = p >> 4, k = p & 15;
    float d = outx[p] - feats[indS[i] * DIN + k];
    acc_f += d * d;
  }
  float acc_b = 0.f;
  for (int i = 0; i < N; ++i) {
    int basee = i * N - (i * (i - 1)) / 2;
    int rowlen = N - i;
    for (int jq = t; jq < rowlen; jq += 256) {
      int j = i + jq;
      float tv = adj[indS[i] * N + indS[j]];
      float pr = outp[basee + jq];
      float l1 = fmaxf(logf(pr), -100.f);
      float l0 = fmaxf(log1pf(-pr), -100.f);
      acc_b += tv * l1 + (1.f - tv) * l0;
    }
  }
  __shared__ float r1[256], r2[256];
  r1[t] = acc_f; r2[t] = acc_b; __syncthreads();
  for (int s = 128; s > 0; s >>= 1) { if (t < s) { r1[t] += r1[t + s]; r2[t] += r2[t + s]; } __syncthreads(); }
  if (t == 0) {
    float fea = r1[0] / (float)(N * DIN);
    float bce = -r2[0] / (float)EDGE;
    out[0] = bce + kl[0] + fea;
  }
}

extern "C" void kernel_launch(void* const* d_in, const int* in_sizes, int n_in,
                              void* d_out, int out_size, void* d_ws, size_t ws_size,
                              hipStream_t stream) {
  const float* feats = (const float*)d_in[0];
  const float* adj   = (const float*)d_in[1];
  const float* w1    = (const float*)d_in[2];
  const float* w2    = (const float*)d_in[3];
  const float* bn1g  = (const float*)d_in[4];
  const float* bn1b  = (const float*)d_in[5];
  const float* bn2g  = (const float*)d_in[6];
  const float* bn2b  = (const float*)d_in[7];
  const float* e11w  = (const float*)d_in[8];
  const float* e11b  = (const float*)d_in[9];
  const float* e12w  = (const float*)d_in[10];
  const float* e12b  = (const float*)d_in[11];
  const float* d1w   = (const float*)d_in[12];
  const float* d1b   = (const float*)d_in[13];
  const float* d2w   = (const float*)d_in[14];
  const float* d2b   = (const float*)d_in[15];
  const float* eps   = (const float*)d_in[16];

  float* ws   = (float*)d_ws;
  float* h1   = ws + W_H1;
  float* x1   = ws + W_X1;
  float* h2   = ws + W_H2;
  float* gh   = ws + W_GH;
  float* h1d  = ws + W_H1D;
  float* kl   = ws + W_KL;
  float* outp = ws + W_OUTP;
  float* outx = ws + W_OUTX;
  float* recon= ws + W_RECON;
  float* degt = ws + W_DEGT;
  float* degr = ws + W_DEGR;
  float* dt   = ws + W_DT;
  float* dr   = ws + W_DR;
  float* Am   = ws + W_A;
  float* Bm   = ws + W_B;
  float* SdT  = ws + W_SDT;
  float* xa   = ws + W_XA;
  float* xb   = ws + W_XB;
  float* ssp  = ws + W_SSP;
  int*   indp = (int*)(ws + W_IND);
  float* out  = (float*)d_out;

  k_enc1<<<96, 256, 0, stream>>>(adj, feats, w1, h1);
  k_bn1<<<256, 128, 0, stream>>>(h1, bn1g, bn1b, x1);
  k_enc2<<<96, 256, 0, stream>>>(adj, x1, w2, h2);
  k_bn2gh<<<256, 128, 0, stream>>>(h2, bn2g, bn2b, gh);
  k_vae<<<1, 128, 0, stream>>>(gh, e11w, e11b, e12w, e12b, d1w, d1b, eps, h1d, kl);
  k_dec<<<25, 256, 0, stream>>>(d2w, d2b, h1d, outp, outx);
  k_recon<<<96, 128, 0, stream>>>(adj, outp, recon, degt, degr, dt, dr);
  k_simab<<<96, 128, 0, stream>>>(adj, recon, degt, degr, dt, dr, Am, Bm, SdT, xa);

  for (int m = 0; m < 50; ++m) {
    const float* xi = (m & 1) ? xb : xa;
    float* xo       = (m & 1) ? xa : xb;
    float* sc       = ssp + (m & 1) * N;
    const float* sp = ssp + ((m & 1) ^ 1) * N;
    k_mpm<<<96, 128, 0, stream>>>(xi, xo, sp, sc, Bm, SdT, Am, (m == 0) ? 1 : 0);
  }
  // m=49 is odd -> final x in xa
  k_greedy<<<1, 256, 0, stream>>>(xa, indp);
  k_loss<<<1, 256, 0, stream>>>(adj, feats, outp, outx, indp, kl, out);
}